// Round 2
// baseline (246.630 us; speedup 1.0000x reference)
//
#include <hip/hip_runtime.h>

#define IN_DIM 8192
#define OUT_DIM 8192
#define NROWS 4096
#define THREADS 1024
#define GRID 256
#define RPB (NROWS / GRID)            // 16 rows per persistent block
#define JG (OUT_DIM / (THREADS * 4))  // 2 j-groups of 4 consecutive j per thread

static_assert(GRID * RPB == NROWS, "row partition");
static_assert(JG * THREADS * 4 == OUT_DIM, "col partition");

typedef float v4f __attribute__((ext_vector_type(4)));

// LDS-only block sync: drain this wave's DS ops, barrier. Global loads/stores
// stay in flight (no vmcnt(0) mid-loop). Clobbers pin memory-op order.
#define BLOCK_SYNC_LDS()                                   \
  do {                                                     \
    asm volatile("s_waitcnt lgkmcnt(0)" ::: "memory");     \
    __builtin_amdgcn_s_barrier();                          \
    asm volatile("" ::: "memory");                         \
  } while (0)

// softmax(weights[j,:16]) @ GATE_COEF for 4 consecutive j.
static __device__ __forceinline__ void softmax_c(const float* __restrict__ w, int jbase,
                                                 v4f* C0, v4f* C1, v4f* C2, v4f* C3) {
  static constexpr float G[16][4] = {
      {0.f, 0.f, 0.f, 0.f}, {0.f, 0.f, 0.f, 1.f}, {0.f, 1.f, 0.f, -1.f}, {0.f, 1.f, 0.f, 0.f},
      {0.f, 0.f, 1.f, -1.f}, {0.f, 0.f, 1.f, 0.f}, {0.f, 1.f, 1.f, -2.f}, {0.f, 1.f, 1.f, -1.f},
      {1.f, -1.f, -1.f, 1.f}, {1.f, -1.f, -1.f, 2.f}, {1.f, 0.f, -1.f, 0.f}, {1.f, 0.f, -1.f, 1.f},
      {1.f, -1.f, 0.f, 0.f}, {1.f, -1.f, 0.f, 1.f}, {1.f, 0.f, 0.f, -1.f}, {1.f, 0.f, 0.f, 0.f}};
#pragma unroll
  for (int q = 0; q < 4; ++q) {
    const float4* wp = (const float4*)(w + (size_t)(jbase + q) * 16);
    float4 w0 = wp[0], w1 = wp[1], w2 = wp[2], w3 = wp[3];
    float wa[16] = {w0.x, w0.y, w0.z, w0.w, w1.x, w1.y, w1.z, w1.w,
                    w2.x, w2.y, w2.z, w2.w, w3.x, w3.y, w3.z, w3.w};
    float m = wa[0];
#pragma unroll
    for (int k = 1; k < 16; ++k) m = fmaxf(m, wa[k]);
    float s = 0.f;
    float p[16];
#pragma unroll
    for (int k = 0; k < 16; ++k) { p[k] = __expf(wa[k] - m); s += p[k]; }
    const float inv = 1.f / s;
    float a0 = 0.f, a1 = 0.f, a2 = 0.f, a3 = 0.f;
#pragma unroll
    for (int k = 0; k < 16; ++k) {
      a0 = fmaf(p[k], G[k][0], a0);
      a1 = fmaf(p[k], G[k][1], a1);
      a2 = fmaf(p[k], G[k][2], a2);
      a3 = fmaf(p[k], G[k][3], a3);
    }
    (*C0)[q] = a0 * inv; (*C1)[q] = a1 * inv; (*C2)[q] = a2 * inv; (*C3)[q] = a3 * inv;
  }
}

// Fused persistent kernel, reg-staged double-buffered row pipeline.
// Per iteration p: ds_write row p+1 (from regs), issue loads row p+2 (to regs),
// compute row p from LDS, LDS-only barrier. Compiler owns all vmcnt tracking.
__global__ __launch_bounds__(THREADS, 4) void gate_fused(
    const float* __restrict__ x, const float* __restrict__ w,
    const int* __restrict__ idx0, const int* __restrict__ idx1,
    float* __restrict__ out) {
  __shared__ __align__(16) float buf[2][IN_DIM];  // 2 x 32 KB
  const int tid = threadIdx.x;
  const int r0 = blockIdx.x * RPB;

  // ---- hoist idx + softmax-c into registers (row-invariant per thread) ----
  int4 i0[JG], i1[JG];
  v4f C0[JG], C1[JG], C2[JG], C3[JG];
#pragma unroll
  for (int g = 0; g < JG; ++g) {
    const int j = tid * 4 + g * (THREADS * 4);
    i0[g] = *(const int4*)(idx0 + j);
    i1[g] = *(const int4*)(idx1 + j);
    softmax_c(w, j, &C0[g], &C1[g], &C2[g], &C3[g]);
  }

  // ---- prologue: row0 -> buf[0] (via regs), row1 loads in flight ----
  v4f ra[2];
  const float* x0 = x + (size_t)r0 * IN_DIM;
#pragma unroll
  for (int t = 0; t < 2; ++t) ra[t] = __builtin_nontemporal_load((const v4f*)x0 + tid + t * THREADS);
#pragma unroll
  for (int t = 0; t < 2; ++t) ((v4f*)buf[0])[tid + t * THREADS] = ra[t];
#pragma unroll
  for (int t = 0; t < 2; ++t)
    ra[t] = __builtin_nontemporal_load((const v4f*)(x0 + IN_DIM) + tid + t * THREADS);
  BLOCK_SYNC_LDS();

#pragma unroll 1
  for (int p = 0; p < RPB; ++p) {
    // (1) publish row p+1 into the other buffer (WAR-safe: end-of-(p-1) barrier)
    if (p + 1 < RPB) {
      v4f* dst = (v4f*)buf[(p + 1) & 1];
#pragma unroll
      for (int t = 0; t < 2; ++t) dst[tid + t * THREADS] = ra[t];
    }
    // (2) issue row p+2 global loads; ~2 row-periods to land
    if (p + 2 < RPB) {
      const float* xs = x + (size_t)(r0 + p + 2) * IN_DIM;
#pragma unroll
      for (int t = 0; t < 2; ++t)
        ra[t] = __builtin_nontemporal_load((const v4f*)xs + tid + t * THREADS);
    }
    // (3) compute row p from buf[p&1]
    const float* bufc = buf[p & 1];
    float* o = out + (size_t)(r0 + p) * OUT_DIM;
#pragma unroll
    for (int g = 0; g < JG; ++g) {
      const int4 ia = i0[g], ib = i1[g];
      v4f a, b;
      a.x = bufc[ia.x]; a.y = bufc[ia.y]; a.z = bufc[ia.z]; a.w = bufc[ia.w];
      b.x = bufc[ib.x]; b.y = bufc[ib.y]; b.z = bufc[ib.z]; b.w = bufc[ib.w];
      const v4f r = C0[g] + C1[g] * a + C2[g] * b + C3[g] * (a * b);
      __builtin_nontemporal_store(r, (v4f*)(o + tid * 4 + g * (THREADS * 4)));
    }
    // (4) LDS-only sync: ds ops drained, global traffic stays in flight
    BLOCK_SYNC_LDS();
  }
}

extern "C" void kernel_launch(void* const* d_in, const int* in_sizes, int n_in,
                              void* d_out, int out_size, void* d_ws, size_t ws_size,
                              hipStream_t stream) {
  const float* x = (const float*)d_in[0];
  const float* weights = (const float*)d_in[1];
  const int* idx0 = (const int*)d_in[2];
  const int* idx1 = (const int*)d_in[3];
  float* out = (float*)d_out;
  gate_fused<<<GRID, THREADS, 0, stream>>>(x, weights, idx0, idx1, out);
}

// Round 3
// 237.973 us; speedup vs baseline: 1.0364x; 1.0364x over previous
//
#include <hip/hip_runtime.h>

#define IN_DIM 8192
#define OUT_DIM 8192
#define NROWS 4096
#define THREADS 512
#define GRID 512
#define RPB (NROWS / GRID)            // 8 rows per persistent block
#define JG (OUT_DIM / (THREADS * 4))  // 4 j-groups of 4 consecutive j per thread
#define SV (IN_DIM / (THREADS * 4))   // 4 v4f staging regs per thread per row

static_assert(GRID * RPB == NROWS, "row partition");
static_assert(JG * THREADS * 4 == OUT_DIM, "col partition");
static_assert(SV * THREADS * 4 == IN_DIM, "stage partition");

typedef float v4f __attribute__((ext_vector_type(4)));

// LDS-only block sync: drain this wave's DS ops, barrier. Global loads/stores
// stay in flight (no vmcnt(0) mid-loop). Clobbers pin memory-op order.
#define BLOCK_SYNC_LDS()                                   \
  do {                                                     \
    asm volatile("s_waitcnt lgkmcnt(0)" ::: "memory");     \
    __builtin_amdgcn_s_barrier();                          \
    asm volatile("" ::: "memory");                         \
  } while (0)

__device__ __constant__ float GATE_COEF[16][4] = {
    {0.f, 0.f, 0.f, 0.f}, {0.f, 0.f, 0.f, 1.f}, {0.f, 1.f, 0.f, -1.f}, {0.f, 1.f, 0.f, 0.f},
    {0.f, 0.f, 1.f, -1.f}, {0.f, 0.f, 1.f, 0.f}, {0.f, 1.f, 1.f, -2.f}, {0.f, 1.f, 1.f, -1.f},
    {1.f, -1.f, -1.f, 1.f}, {1.f, -1.f, -1.f, 2.f}, {1.f, 0.f, -1.f, 0.f}, {1.f, 0.f, -1.f, 1.f},
    {1.f, -1.f, 0.f, 0.f}, {1.f, -1.f, 0.f, 1.f}, {1.f, 0.f, 0.f, -1.f}, {1.f, 0.f, 0.f, 0.f}};

// Kernel A: c[j] = softmax(weights[j,:]) @ GATE_COEF, stored SoA (4 planes of
// OUT_DIM floats) so gate kernel's per-row c reloads are coalesced v4f loads.
__global__ __launch_bounds__(256) void compute_c_kernel(const float* __restrict__ w,
                                                        float* __restrict__ cp) {
  int j = blockIdx.x * blockDim.x + threadIdx.x;
  if (j >= OUT_DIM) return;
  const float4* wv = (const float4*)(w + (size_t)j * 16);
  float4 w0 = wv[0], w1 = wv[1], w2 = wv[2], w3 = wv[3];
  float wa[16] = {w0.x, w0.y, w0.z, w0.w, w1.x, w1.y, w1.z, w1.w,
                  w2.x, w2.y, w2.z, w2.w, w3.x, w3.y, w3.z, w3.w};
  float m = wa[0];
#pragma unroll
  for (int k = 1; k < 16; ++k) m = fmaxf(m, wa[k]);
  float p[16];
  float s = 0.f;
#pragma unroll
  for (int k = 0; k < 16; ++k) {
    p[k] = __expf(wa[k] - m);
    s += p[k];
  }
  float inv = 1.f / s;
  float c0 = 0.f, c1 = 0.f, c2 = 0.f, c3 = 0.f;
#pragma unroll
  for (int k = 0; k < 16; ++k) {
    c0 = fmaf(p[k], GATE_COEF[k][0], c0);
    c1 = fmaf(p[k], GATE_COEF[k][1], c1);
    c2 = fmaf(p[k], GATE_COEF[k][2], c2);
    c3 = fmaf(p[k], GATE_COEF[k][3], c3);
  }
  cp[j] = c0 * inv;
  cp[j + OUT_DIM] = c1 * inv;
  cp[j + 2 * OUT_DIM] = c2 * inv;
  cp[j + 3 * OUT_DIM] = c3 * inv;
}

// Kernel B: persistent row pipeline, 2 co-resident blocks/CU (512 blocks x 512
// threads, 64 KB LDS each -> all blocks resident: perfect balance + cross-block
// overlap at barriers). idx hoisted to regs (row-invariant per thread); c
// reloaded per row from L2-resident SoA planes. Rows double-buffered via regs;
// LDS-only barrier per row -- global loads/stores never drained mid-loop.
__global__ __launch_bounds__(THREADS, 4) void gate_persist(
    const float* __restrict__ x, const float* __restrict__ cp,
    const int* __restrict__ idx0, const int* __restrict__ idx1,
    float* __restrict__ out) {
  __shared__ __align__(16) float buf[2][IN_DIM];  // 2 x 32 KB
  const int tid = threadIdx.x;
  const int r0 = blockIdx.x * RPB;

  // ---- hoist idx into registers (row-invariant per thread): 32 VGPR ----
  int4 i0[JG], i1[JG];
#pragma unroll
  for (int g = 0; g < JG; ++g) {
    const int j = tid * 4 + g * (THREADS * 4);
    i0[g] = *(const int4*)(idx0 + j);
    i1[g] = *(const int4*)(idx1 + j);
  }

  const float* c0p = cp;
  const float* c1p = cp + OUT_DIM;
  const float* c2p = cp + 2 * OUT_DIM;
  const float* c3p = cp + 3 * OUT_DIM;

  // ---- prologue: row0 -> buf[0] (via regs), row1 loads left in flight ----
  v4f ra[SV];
  const float* x0 = x + (size_t)r0 * IN_DIM;
#pragma unroll
  for (int t = 0; t < SV; ++t)
    ra[t] = __builtin_nontemporal_load((const v4f*)x0 + tid + t * THREADS);
#pragma unroll
  for (int t = 0; t < SV; ++t) ((v4f*)buf[0])[tid + t * THREADS] = ra[t];
#pragma unroll
  for (int t = 0; t < SV; ++t)
    ra[t] = __builtin_nontemporal_load((const v4f*)(x0 + IN_DIM) + tid + t * THREADS);
  BLOCK_SYNC_LDS();

#pragma unroll 1
  for (int p = 0; p < RPB; ++p) {
    // (1) publish row p+1 into the other buffer (WAR-safe: end-of-(p-1) barrier)
    if (p + 1 < RPB) {
      v4f* dst = (v4f*)buf[(p + 1) & 1];
#pragma unroll
      for (int t = 0; t < SV; ++t) dst[tid + t * THREADS] = ra[t];
    }
    // (2) issue row p+2 global loads; one full row-period to land
    if (p + 2 < RPB) {
      const float* xs = x + (size_t)(r0 + p + 2) * IN_DIM;
#pragma unroll
      for (int t = 0; t < SV; ++t)
        ra[t] = __builtin_nontemporal_load((const v4f*)xs + tid + t * THREADS);
    }
    // (3) compute row p from buf[p&1]; c reloaded (coalesced, L2-resident)
    const float* bufc = buf[p & 1];
    float* o = out + (size_t)(r0 + p) * OUT_DIM;
#pragma unroll
    for (int g = 0; g < JG; ++g) {
      const int j = tid * 4 + g * (THREADS * 4);
      const v4f c0v = *(const v4f*)(c0p + j);
      const v4f c1v = *(const v4f*)(c1p + j);
      const v4f c2v = *(const v4f*)(c2p + j);
      const v4f c3v = *(const v4f*)(c3p + j);
      const int4 ia = i0[g], ib = i1[g];
      v4f a, b;
      a.x = bufc[ia.x]; a.y = bufc[ia.y]; a.z = bufc[ia.z]; a.w = bufc[ia.w];
      b.x = bufc[ib.x]; b.y = bufc[ib.y]; b.z = bufc[ib.z]; b.w = bufc[ib.w];
      const v4f r = c0v + c1v * a + c2v * b + c3v * (a * b);
      __builtin_nontemporal_store(r, (v4f*)(o + j));
    }
    // (4) LDS-only sync: ds ops drained, global traffic stays in flight
    BLOCK_SYNC_LDS();
  }
}

extern "C" void kernel_launch(void* const* d_in, const int* in_sizes, int n_in,
                              void* d_out, int out_size, void* d_ws, size_t ws_size,
                              hipStream_t stream) {
  const float* x = (const float*)d_in[0];
  const float* weights = (const float*)d_in[1];
  const int* idx0 = (const int*)d_in[2];
  const int* idx1 = (const int*)d_in[3];
  float* out = (float*)d_out;
  float* cp = (float*)d_ws;  // 4 planes x OUT_DIM floats = 128 KB scratch

  compute_c_kernel<<<OUT_DIM / 256, 256, 0, stream>>>(weights, cp);
  gate_persist<<<GRID, THREADS, 0, stream>>>(x, cp, idx0, idx1, out);
}